// Round 4
// baseline (365.035 us; speedup 1.0000x reference)
//
#include <hip/hip_runtime.h>
#include <hip/hip_bf16.h>
#include <math.h>

typedef __attribute__((ext_vector_type(8))) short short8;
typedef __attribute__((ext_vector_type(4))) short short4v;
typedef __attribute__((ext_vector_type(4))) float f32x4;
typedef unsigned short u16;

#define S_LEN 2048
#define D_HEAD 64
#define C2 0.18033688011112043f   /* log2(e)/8 */

static __device__ __forceinline__ u16 f2bf(float x) {
    union { float f; unsigned u; } a; a.f = x;
    unsigned r = a.u + (0x7fffu + ((a.u >> 16) & 1u));   // RNE
    return (u16)(r >> 16);
}
static __device__ __forceinline__ float bf2f(u16 h) {
    union { unsigned u; float f; } a; a.u = ((unsigned)h) << 16;
    return a.f;
}
static __device__ __forceinline__ u16 bfbits(float x) {
    __hip_bfloat16 h = __float2bfloat16(x);
    return __builtin_bit_cast(unsigned short, h);
}
static __device__ __forceinline__ float exp2v(float x) { // v_exp_f32 = 2^x
    float r; asm("v_exp_f32 %0, %1" : "=v"(r) : "v"(x)); return r;
}

// ---- prep: T5 bias baked to [h][delta+2047], pre-scaled by log2(e)/8 ----
__global__ void prep_bias(const float* __restrict__ table, float* __restrict__ bias_d) {
    int idx = blockIdx.x * blockDim.x + threadIdx.x;   // 0..4095
    if (idx >= 4096) return;
    int delta = idx - 2047;                 // k - q
    int bpos = (delta > 0) ? 16 : 0;
    int ad = delta < 0 ? -delta : delta;
    int rel;
    if (ad < 8) {
        rel = bpos + ad;
    } else {
        float rp = (float)ad;
        int lg = 8 + (int)(logf(rp / 8.0f) / 2.772588722239781f * 8.0f);  // log(16)
        if (lg > 15) lg = 15;
        rel = bpos + lg;
    }
    #pragma unroll
    for (int h = 0; h < 4; ++h)
        bias_d[h * 4096 + idx] = C2 * table[rel * 4 + h];
}

// ---- prep: elementwise fp32 -> bf16 hi/lo split (for K) ----
__global__ void prep_split(const float* __restrict__ src, u16* __restrict__ hi,
                           u16* __restrict__ lo) {
    size_t i8 = ((size_t)blockIdx.x * 256 + threadIdx.x) * 8;
    f32x4 a = *(const f32x4*)(src + i8);
    f32x4 b = *(const f32x4*)(src + i8 + 4);
    float xs[8] = {a[0], a[1], a[2], a[3], b[0], b[1], b[2], b[3]};
    short8 hv, lv;
    #pragma unroll
    for (int i = 0; i < 8; ++i) {
        u16 hb = f2bf(xs[i]);
        hv[i] = (short)hb;
        lv[i] = (short)f2bf(xs[i] - bf2f(hb));
    }
    *(short8*)(hi + i8) = hv;
    *(short8*)(lo + i8) = lv;
}

// ---- prep: V [bh][k][d] fp32  ->  V^T hi/lo bf16 [bh][d][k] ----
__global__ void prep_vt(const float* __restrict__ V, u16* __restrict__ vthi,
                        u16* __restrict__ vtlo) {
    __shared__ float tile[64][65];
    const int bh = blockIdx.y;
    const int k0 = blockIdx.x * 64;
    const int t = threadIdx.x;
    {
        int r = t >> 2, c0 = (t & 3) * 16;
        const float* src = V + ((size_t)bh * S_LEN + k0 + r) * D_HEAD + c0;
        #pragma unroll
        for (int i = 0; i < 16; i += 4) {
            f32x4 v = *(const f32x4*)(src + i);
            tile[r][c0 + i + 0] = v[0];
            tile[r][c0 + i + 1] = v[1];
            tile[r][c0 + i + 2] = v[2];
            tile[r][c0 + i + 3] = v[3];
        }
    }
    __syncthreads();
    {
        int d = t >> 2, kc = (t & 3) * 16;
        size_t ob = ((size_t)bh * D_HEAD + d) * S_LEN + k0 + kc;
        #pragma unroll
        for (int half = 0; half < 2; ++half) {
            short8 hv, lv;
            #pragma unroll
            for (int i = 0; i < 8; ++i) {
                float x = tile[kc + half * 8 + i][d];
                u16 hb = f2bf(x);
                hv[i] = (short)hb;
                lv[i] = (short)f2bf(x - bf2f(hb));
            }
            *(short8*)(vthi + ob + half * 8) = hv;
            *(short8*)(vtlo + ob + half * 8) = lv;
        }
    }
}

// ============================================================================
// main: two-pass fused attention, log2-domain max-free softmax.
// BARRIER-FREE streaming: all K/V MFMA fragments are loaded directly
// global->VGPR (K/V are L1/L2-resident; FETCH_SIZE proved 12.5 MB HBM).
// No LDS staging, no in-loop __syncthreads. A raw s_barrier (no memory
// drain) per iter keeps the 4 wq-waves phase-aligned for L1 reuse.
// LDS 27KB: Q hi/lo stage 16KB (aliased by epilogue reduce), stats 512B,
// per-wave p-hi buffer 8x1280B (stride-40 rows, conflict-free).
// ============================================================================
__launch_bounds__(512, 4)
__global__ void attn_main(const float* __restrict__ Q, const int* __restrict__ mask,
                          const float* __restrict__ bias2,
                          const u16* __restrict__ khi_g, const u16* __restrict__ klo_g,
                          const u16* __restrict__ vhi_g, const u16* __restrict__ vlo_g,
                          float* __restrict__ outp, float* __restrict__ p_out) {
    __shared__ __align__(16) char smem[27648];
    u16* qh = (u16*)smem;                     // [64][64] bf16 hi
    u16* ql = (u16*)(smem + 8192);            // [64][64] bf16 lo
    float* stats = (float*)(smem + 16384);    // 128 floats
    u16* pball = (u16*)(smem + 16896);        // 8 waves x 640 u16

    const int tid = threadIdx.x;
    const int w = tid >> 6, l = tid & 63;
    const int wq = w & 3, wk = w >> 2;
    const int g = l >> 4, lq = l & 15;
    const int r7 = lq & 7;
    const int bid = blockIdx.x;
    const int bh = bid & 15, b = bh >> 2, h = bh & 3;   // bid%8 == bh%8: bh pinned per XCD
    const int q0 = (bid >> 4) * 64;

    const float* Qp = Q + (size_t)bh * (S_LEN * D_HEAD);
    const int* mp = mask + b * S_LEN;
    const u16* khp = khi_g + (size_t)bh * (S_LEN * D_HEAD);
    const u16* klp = klo_g + (size_t)bh * (S_LEN * D_HEAD);
    const u16* vhp = vhi_g + (size_t)bh * (S_LEN * D_HEAD);
    const u16* vlp = vlo_g + (size_t)bh * (S_LEN * D_HEAD);

    // ---- stage Q -> bf16 hi/lo in LDS (swizzled, as r3), read frags, done ----
    {
        int sr = tid >> 3, tb = tid & 7;
        const float* src = Qp + (size_t)(q0 + sr) * D_HEAD + tb * 8;
        f32x4 a = *(const f32x4*)src;
        f32x4 c = *(const f32x4*)(src + 4);
        float xs[8] = {a[0], a[1], a[2], a[3], c[0], c[1], c[2], c[3]};
        short8 hv, lv;
        #pragma unroll
        for (int i = 0; i < 8; ++i) {
            u16 hb = f2bf(xs[i]);
            hv[i] = (short)hb;
            lv[i] = (short)f2bf(xs[i] - bf2f(hb));
        }
        int dst = sr * 64 + ((tb ^ (sr & 7)) * 8);
        *(short8*)(qh + dst) = hv;
        *(short8*)(ql + dst) = lv;
    }
    __syncthreads();

    short8 qfh[2], qfl[2];
    const int qrow = 16 * wq + lq;
    #pragma unroll
    for (int c = 0; c < 2; ++c) {
        int blk = ((4 * c + g) ^ r7) * 8;
        qfh[c] = *(const short8*)(qh + qrow * 64 + blk);
        qfl[c] = *(const short8*)(ql + qrow * 64 + blk);
    }
    const int qq = q0 + qrow;

    // ================= PASS 1: l = sum(2^s2); K-hi direct from global =================
    // per-lane frag addr: khp + (kb + 64*wk + 16*t2 + lq)*64 + 32*c + 8*g
    const u16* kA = khp + (size_t)(64 * wk + lq) * 64 + 8 * g;
    const int* mP1 = mp + 64 * wk + 4 * g;
    const float* bP1 = bias2 + h * 4096 + 2047 - qq + 64 * wk + 4 * g;
    float lsum = 0.0f;
    for (int t = 0; t < 16; ++t) {
        __builtin_amdgcn_s_barrier();    // raw: phase-align waves for L1 reuse
        #pragma unroll
        for (int t2 = 0; t2 < 4; ++t2) {
            short8 a0 = *(const short8*)(kA + t2 * 1024);
            short8 a1 = *(const short8*)(kA + t2 * 1024 + 32);
            f32x4 acc = {0.f, 0.f, 0.f, 0.f};
            acc = __builtin_amdgcn_mfma_f32_16x16x32_bf16(a0, qfh[0], acc, 0, 0, 0);
            acc = __builtin_amdgcn_mfma_f32_16x16x32_bf16(a1, qfh[1], acc, 0, 0, 0);
            const int4 mv = *(const int4*)(mP1 + 16 * t2);
            float s0 = mv.x ? fmaf(acc[0], C2, bP1[16 * t2 + 0]) : -1e9f;
            float s1 = mv.y ? fmaf(acc[1], C2, bP1[16 * t2 + 1]) : -1e9f;
            float s2 = mv.z ? fmaf(acc[2], C2, bP1[16 * t2 + 2]) : -1e9f;
            float s3 = mv.w ? fmaf(acc[3], C2, bP1[16 * t2 + 3]) : -1e9f;
            lsum += exp2v(s0) + exp2v(s1) + exp2v(s2) + exp2v(s3);
        }
        kA += 8192; mP1 += 128; bP1 += 128;
    }
    lsum += __shfl_xor(lsum, 16);
    lsum += __shfl_xor(lsum, 32);
    if (g == 0) stats[wk * 64 + qrow] = lsum;
    __syncthreads();
    float lr2q;
    {
        float L = stats[qrow] + stats[64 + qrow];
        float lg; asm("v_log_f32 %0, %1" : "=v"(lg) : "v"(L));
        lr2q = -lg;    // p = 2^(s2 + lr2q)
    }

    // ================= PASS 2: p = 2^(s2+lr2), write p, PV (P-hi x V-hi/lo) =================
    f32x4 acco[4] = {{0.f,0.f,0.f,0.f},{0.f,0.f,0.f,0.f},{0.f,0.f,0.f,0.f},{0.f,0.f,0.f,0.f}};
    // K frag: khp + (kb + 32*wk + 16*t2 + lq)*64 + 32*c + 8*g
    const u16* kH = khp + (size_t)(32 * wk + lq) * 64 + 8 * g;
    const u16* kL = klp + (size_t)(32 * wk + lq) * 64 + 8 * g;
    // V^T frag: vhp + (16*n + lq)*2048 + kb + 32*wk + 8*g
    const u16* vH = vhp + (size_t)lq * 2048 + 32 * wk + 8 * g;
    const u16* vL = vlp + (size_t)lq * 2048 + 32 * wk + 8 * g;
    const int* mP = mp + 32 * wk + 4 * g;
    const float* bP = bias2 + h * 4096 + 2047 - qq + 32 * wk + 4 * g;
    float* pP = p_out + (size_t)bh * (S_LEN * S_LEN) + (size_t)qq * S_LEN + 32 * wk + 4 * g;
    u16* pwr = pball + w * 640 + lq * 40 + g * 4;       // p write (+t2*16)
    const u16* prd = pball + w * 640 + lq * 40 + g * 8; // p frag read

    for (int t = 0; t < 32; ++t) {
        __builtin_amdgcn_s_barrier();    // raw: phase-align waves for L1 reuse
        #pragma unroll
        for (int t2 = 0; t2 < 2; ++t2) {
            short8 ah0 = *(const short8*)(kH + t2 * 1024);
            short8 ah1 = *(const short8*)(kH + t2 * 1024 + 32);
            short8 al0 = *(const short8*)(kL + t2 * 1024);
            short8 al1 = *(const short8*)(kL + t2 * 1024 + 32);
            f32x4 acc = {0.f, 0.f, 0.f, 0.f};
            acc = __builtin_amdgcn_mfma_f32_16x16x32_bf16(ah0, qfh[0], acc, 0, 0, 0);
            acc = __builtin_amdgcn_mfma_f32_16x16x32_bf16(al0, qfh[0], acc, 0, 0, 0);
            acc = __builtin_amdgcn_mfma_f32_16x16x32_bf16(ah0, qfl[0], acc, 0, 0, 0);
            acc = __builtin_amdgcn_mfma_f32_16x16x32_bf16(ah1, qfh[1], acc, 0, 0, 0);
            acc = __builtin_amdgcn_mfma_f32_16x16x32_bf16(al1, qfh[1], acc, 0, 0, 0);
            acc = __builtin_amdgcn_mfma_f32_16x16x32_bf16(ah1, qfl[1], acc, 0, 0, 0);
            const int4 mv = *(const int4*)(mP + 16 * t2);
            float p0 = exp2v(mv.x ? fmaf(acc[0], C2, bP[16 * t2 + 0]) + lr2q : -1e9f);
            float p1 = exp2v(mv.y ? fmaf(acc[1], C2, bP[16 * t2 + 1]) + lr2q : -1e9f);
            float p2 = exp2v(mv.z ? fmaf(acc[2], C2, bP[16 * t2 + 2]) + lr2q : -1e9f);
            float p3 = exp2v(mv.w ? fmaf(acc[3], C2, bP[16 * t2 + 3]) + lr2q : -1e9f);
            f32x4 pw = {p0, p1, p2, p3};
            __builtin_nontemporal_store(pw, (f32x4*)(pP + 16 * t2));
            short4v ph4;
            ph4[0] = (short)bfbits(p0);
            ph4[1] = (short)bfbits(p1);
            ph4[2] = (short)bfbits(p2);
            ph4[3] = (short)bfbits(p3);
            *(short4v*)(pwr + 16 * t2) = ph4;
        }
        // PV: A = P-hi [16q x 32k] (own wave's LDS), B = V^T hi/lo from global
        const short8 pf = *(const short8*)prd;
        #pragma unroll
        for (int n = 0; n < 4; ++n) {
            short8 bhf = *(const short8*)(vH + n * 32768);
            short8 blf = *(const short8*)(vL + n * 32768);
            acco[n] = __builtin_amdgcn_mfma_f32_16x16x32_bf16(pf, bhf, acco[n], 0, 0, 0);
            acco[n] = __builtin_amdgcn_mfma_f32_16x16x32_bf16(pf, blf, acco[n], 0, 0, 0);
        }
        kH += 4096; kL += 4096; vH += 64; vL += 64;
        mP += 64; bP += 64; pP += 64;
    }

    // ---- reduce the two wk halves and store out (ored aliases Q area; safe:
    //      all Q-frag reads happened before the stats barrier) ----
    float* ored = (float*)smem;    // [64 q][64 d]
    __syncthreads();
    if (wk == 1) {
        #pragma unroll
        for (int n = 0; n < 4; ++n)
            #pragma unroll
            for (int r = 0; r < 4; ++r)
                ored[(wq * 16 + 4 * g + r) * 64 + 16 * n + lq] = acco[n][r];
    }
    __syncthreads();
    if (wk == 0) {
        #pragma unroll
        for (int n = 0; n < 4; ++n) {
            #pragma unroll
            for (int r = 0; r < 4; ++r) {
                float v = acco[n][r] + ored[(wq * 16 + 4 * g + r) * 64 + 16 * n + lq];
                outp[((size_t)bh * S_LEN + q0 + 16 * wq + 4 * g + r) * D_HEAD + 16 * n + lq] = v;
            }
        }
    }
}

extern "C" void kernel_launch(void* const* d_in, const int* in_sizes, int n_in,
                              void* d_out, int out_size, void* d_ws, size_t ws_size,
                              hipStream_t stream) {
    const float* Q = (const float*)d_in[0];
    const float* K = (const float*)d_in[1];
    const float* V = (const float*)d_in[2];
    const int* mask = (const int*)d_in[3];
    const float* table = (const float*)d_in[4];

    float* outp = (float*)d_out;
    float* p_out = outp + (size_t)4 * 4 * 2048 * 64;   // out first, then p_attn

    float* bias_d = (float*)d_ws;                                   // 64 KB
    u16* khi = (u16*)((char*)d_ws + 65536);                         // 4 MB each
    u16* klo = khi + (size_t)16 * S_LEN * D_HEAD;
    u16* vthi = klo + (size_t)16 * S_LEN * D_HEAD;
    u16* vtlo = vthi + (size_t)16 * S_LEN * D_HEAD;

    prep_bias<<<16, 256, 0, stream>>>(table, bias_d);
    prep_split<<<1024, 256, 0, stream>>>(K, khi, klo);
    prep_vt<<<dim3(32, 16), 256, 0, stream>>>(V, vthi, vtlo);
    attn_main<<<512, 512, 0, stream>>>(Q, mask, bias_d, khi, klo, vthi, vtlo, outp, p_out);
}

// Round 5
// 136.132 us; speedup vs baseline: 2.6815x; 2.6815x over previous
//
#include <hip/hip_runtime.h>
#include <hip/hip_bf16.h>
#include <math.h>

typedef __attribute__((ext_vector_type(8))) short short8;
typedef __attribute__((ext_vector_type(4))) short short4v;
typedef __attribute__((ext_vector_type(4))) float f32x4;
typedef unsigned short u16;

#define S_LEN 2048
#define D_HEAD 64
#define C2 0.18033688011112043f   /* log2(e)/8 */

static __device__ __forceinline__ u16 f2bf(float x) {
    union { float f; unsigned u; } a; a.f = x;
    unsigned r = a.u + (0x7fffu + ((a.u >> 16) & 1u));   // RNE
    return (u16)(r >> 16);
}
static __device__ __forceinline__ float bf2f(u16 h) {
    union { unsigned u; float f; } a; a.u = ((unsigned)h) << 16;
    return a.f;
}
static __device__ __forceinline__ u16 bfbits(float x) {
    __hip_bfloat16 h = __float2bfloat16(x);
    return __builtin_bit_cast(unsigned short, h);
}
static __device__ __forceinline__ float exp2v(float x) { // v_exp_f32 = 2^x
    float r; asm("v_exp_f32 %0, %1" : "=v"(r) : "v"(x)); return r;
}

static __device__ __forceinline__ void gl_lds16(const void* g, void* l) {
    __builtin_amdgcn_global_load_lds(
        (const __attribute__((address_space(1))) unsigned int*)g,
        (__attribute__((address_space(3))) unsigned int*)l, 16, 0, 0);
}

// ---- prep: T5 bias baked to [h][delta+2047], pre-scaled by log2(e)/8 ----
__global__ void prep_bias(const float* __restrict__ table, float* __restrict__ bias_d) {
    int idx = blockIdx.x * blockDim.x + threadIdx.x;   // 0..4095
    if (idx >= 4096) return;
    int delta = idx - 2047;                 // k - q
    int bpos = (delta > 0) ? 16 : 0;
    int ad = delta < 0 ? -delta : delta;
    int rel;
    if (ad < 8) {
        rel = bpos + ad;
    } else {
        float rp = (float)ad;
        int lg = 8 + (int)(logf(rp / 8.0f) / 2.772588722239781f * 8.0f);  // log(16)
        if (lg > 15) lg = 15;
        rel = bpos + lg;
    }
    #pragma unroll
    for (int h = 0; h < 4; ++h)
        bias_d[h * 4096 + idx] = C2 * table[rel * 4 + h];
}

// ---- prep: elementwise fp32 -> bf16 hi/lo split (for K) ----
__global__ void prep_split(const float* __restrict__ src, u16* __restrict__ hi,
                           u16* __restrict__ lo) {
    size_t i8 = ((size_t)blockIdx.x * 256 + threadIdx.x) * 8;
    f32x4 a = *(const f32x4*)(src + i8);
    f32x4 b = *(const f32x4*)(src + i8 + 4);
    float xs[8] = {a[0], a[1], a[2], a[3], b[0], b[1], b[2], b[3]};
    short8 hv, lv;
    #pragma unroll
    for (int i = 0; i < 8; ++i) {
        u16 hb = f2bf(xs[i]);
        hv[i] = (short)hb;
        lv[i] = (short)f2bf(xs[i] - bf2f(hb));
    }
    *(short8*)(hi + i8) = hv;
    *(short8*)(lo + i8) = lv;
}

// ---- prep: V [bh][k][d] fp32  ->  V^T hi/lo bf16 [bh][d][k] ----
__global__ void prep_vt(const float* __restrict__ V, u16* __restrict__ vthi,
                        u16* __restrict__ vtlo) {
    __shared__ float tile[64][65];
    const int bh = blockIdx.y;
    const int k0 = blockIdx.x * 64;
    const int t = threadIdx.x;
    {
        int r = t >> 2, c0 = (t & 3) * 16;
        const float* src = V + ((size_t)bh * S_LEN + k0 + r) * D_HEAD + c0;
        #pragma unroll
        for (int i = 0; i < 16; i += 4) {
            f32x4 v = *(const f32x4*)(src + i);
            tile[r][c0 + i + 0] = v[0];
            tile[r][c0 + i + 1] = v[1];
            tile[r][c0 + i + 2] = v[2];
            tile[r][c0 + i + 3] = v[3];
        }
    }
    __syncthreads();
    {
        int d = t >> 2, kc = (t & 3) * 16;
        size_t ob = ((size_t)bh * D_HEAD + d) * S_LEN + k0 + kc;
        #pragma unroll
        for (int half = 0; half < 2; ++half) {
            short8 hv, lv;
            #pragma unroll
            for (int i = 0; i < 8; ++i) {
                float x = tile[kc + half * 8 + i][d];
                u16 hb = f2bf(x);
                hv[i] = (short)hb;
                lv[i] = (short)f2bf(x - bf2f(hb));
            }
            *(short8*)(vthi + ob + half * 8) = hv;
            *(short8*)(vtlo + ob + half * 8) = lv;
        }
    }
}

// ============================================================================
// main: two-pass fused attention, log2-domain max-free softmax.
// r3 structure (LDS-staged, gl_lds width-16, swizzled sources) but with
// COUNTED vmcnt + raw s_barrier per iter (T4/m218): NT p-stores are never
// drained inside the loop, staging loads get the whole iteration to land.
// LDS 76288B: [0..32K) pass1 K-hi dbuf | pass2 buf0; [32K..64K) Q hi/lo
// (pass-0 only) | pass2 buf1; [64K..74.5K) per-wave p buffers;
// [74.5K..75K) stats (dedicated - fixes r3's alias race).
// ============================================================================
__launch_bounds__(512, 4)
__global__ void attn_main(const float* __restrict__ Q, const int* __restrict__ mask,
                          const float* __restrict__ bias2,
                          const u16* __restrict__ khi_g, const u16* __restrict__ klo_g,
                          const u16* __restrict__ vhi_g, const u16* __restrict__ vlo_g,
                          float* __restrict__ outp, float* __restrict__ p_out) {
    __shared__ __align__(16) char smem[76288];
    float* stats = (float*)(smem + 75776);    // 128 floats, aliases nothing

    const int tid = threadIdx.x;
    const int w = tid >> 6, l = tid & 63;
    const int wq = w & 3, wk = w >> 2;
    const int g = l >> 4, lq = l & 15;
    const int r7 = lq & 7;
    const int bid = blockIdx.x;
    const int bh = bid & 15, b = bh >> 2, h = bh & 3;   // bid%8 == bh%8: bh pinned per XCD
    const int q0 = (bid >> 4) * 64;

    const float* Qp = Q + (size_t)bh * (S_LEN * D_HEAD);
    const int* mp = mask + b * S_LEN;
    const u16* khp = khi_g + (size_t)bh * (S_LEN * D_HEAD);
    const u16* klp = klo_g + (size_t)bh * (S_LEN * D_HEAD);
    const u16* vhp = vhi_g + (size_t)bh * (S_LEN * D_HEAD);
    const u16* vlp = vlo_g + (size_t)bh * (S_LEN * D_HEAD);

    // ---- stage Q -> bf16 hi/lo (swizzled ds_write) at smem+32K ----
    u16* qh = (u16*)(smem + 32768);
    u16* ql = (u16*)(smem + 40960);
    {
        int sr = tid >> 3, tb = tid & 7;
        const float* src = Qp + (size_t)(q0 + sr) * D_HEAD + tb * 8;
        f32x4 a = *(const f32x4*)src;
        f32x4 c = *(const f32x4*)(src + 4);
        float xs[8] = {a[0], a[1], a[2], a[3], c[0], c[1], c[2], c[3]};
        short8 hv, lv;
        #pragma unroll
        for (int i = 0; i < 8; ++i) {
            u16 hb = f2bf(xs[i]);
            hv[i] = (short)hb;
            lv[i] = (short)f2bf(xs[i] - bf2f(hb));
        }
        int dst = sr * 64 + ((tb ^ (sr & 7)) * 8);
        *(short8*)(qh + dst) = hv;
        *(short8*)(ql + dst) = lv;
    }

    // hoisted staging geometry (shared by both passes)
    const int rr3 = tid >> 3;                       // chunk row 0..63
    const int ub0 = (((tid & 7) ^ (rr3 & 7)) * 8);  // swizzled 8-elem block
    // pass-1 prologue: stage K-hi rows 0..127 -> smem+0 (16KB)
    const u16* s1a = khp + (size_t)rr3 * 64 + ub0;
    const u16* s1b = s1a + 4096;                    // rows 64..127 ((64+r)&7==r&7)
    gl_lds16(s1a, smem + tid * 16);
    gl_lds16(s1b, smem + 8192 + tid * 16);
    __syncthreads();

    short8 qfh[2], qfl[2];
    const int qrow = 16 * wq + lq;
    #pragma unroll
    for (int c = 0; c < 2; ++c) {
        int blk = ((4 * c + g) ^ r7) * 8;
        qfh[c] = *(const short8*)(qh + qrow * 64 + blk);
        qfl[c] = *(const short8*)(ql + qrow * 64 + blk);
    }
    const int qq = q0 + qrow;

    // ================= PASS 1: l = sum(2^s2), K-tile 128, 16 iters =================
    const int* mP1 = mp + 64 * wk + 4 * g;
    const float* bP1 = bias2 + h * 4096 + 2047 - qq + 64 * wk + 4 * g;
    float lsum = 0.0f;
    for (int t = 0; t < 16; ++t) {
        const u16* kh = (const u16*)(smem + (t & 1) * 16384);
        // hoist mask/bias loads BEFORE staging (keeps gl_lds un-drained by their use-waits)
        int4 mv[4]; float bv[4][4];
        #pragma unroll
        for (int t2 = 0; t2 < 4; ++t2) {
            mv[t2] = *(const int4*)(mP1 + 16 * t2);
            #pragma unroll
            for (int j = 0; j < 4; ++j) bv[t2][j] = bP1[16 * t2 + j];
        }
        if (t < 15) {
            s1a += 8192; s1b += 8192;
            char* nb = smem + ((t + 1) & 1) * 16384 + tid * 16;
            gl_lds16(s1a, nb);
            gl_lds16(s1b, nb + 8192);
        }
        __builtin_amdgcn_sched_barrier(0);   // pin staging issue before compute
        #pragma unroll
        for (int t2 = 0; t2 < 4; ++t2) {
            const int krow = 64 * wk + 16 * t2 + lq;
            f32x4 acc = {0.f, 0.f, 0.f, 0.f};
            #pragma unroll
            for (int c = 0; c < 2; ++c) {
                short8 af = *(const short8*)(kh + krow * 64 + ((4 * c + g) ^ r7) * 8);
                acc = __builtin_amdgcn_mfma_f32_16x16x32_bf16(af, qfh[c], acc, 0, 0, 0);
            }
            float s0 = mv[t2].x ? fmaf(acc[0], C2, bv[t2][0]) : -1e9f;
            float s1 = mv[t2].y ? fmaf(acc[1], C2, bv[t2][1]) : -1e9f;
            float s2 = mv[t2].z ? fmaf(acc[2], C2, bv[t2][2]) : -1e9f;
            float s3 = mv[t2].w ? fmaf(acc[3], C2, bv[t2][3]) : -1e9f;
            lsum += exp2v(s0) + exp2v(s1) + exp2v(s2) + exp2v(s3);
        }
        mP1 += 128; bP1 += 128;
        // counted end-of-iter: staging must have landed; nothing else outstanding
        asm volatile("s_waitcnt vmcnt(0)" ::: "memory");
        __builtin_amdgcn_sched_barrier(0);
        __builtin_amdgcn_s_barrier();
        __builtin_amdgcn_sched_barrier(0);
    }
    lsum += __shfl_xor(lsum, 16);
    lsum += __shfl_xor(lsum, 32);
    if (g == 0) stats[wk * 64 + qrow] = lsum;

    // ---- pass-2 staging pointers + prologue (buf0: Khi,Klo,Vh,Vl) ----
    const u16* sKh = khp + (size_t)rr3 * 64 + ub0;
    const u16* sKl = klp + (size_t)rr3 * 64 + ub0;
    const u16* sVh = vhp + (size_t)rr3 * 2048 + ub0;
    const u16* sVl = vlp + (size_t)rr3 * 2048 + ub0;
    {
        char* d0 = smem + tid * 16;
        gl_lds16(sKh, d0);
        gl_lds16(sKl, d0 + 8192);
        gl_lds16(sVh, d0 + 16384);
        gl_lds16(sVl, d0 + 24576);
    }
    __syncthreads();   // stats visible + buf0 staged (full drain, once)
    float lr2q;
    {
        float L = stats[qrow] + stats[64 + qrow];
        float lg; asm("v_log_f32 %0, %1" : "=v"(lg) : "v"(L));
        lr2q = -lg;    // p = 2^(s2 + lr2q)
    }

    // ================= PASS 2: p = 2^(s2+lr2), write p, PV (P-hi x V-hi/lo) =================
    f32x4 acco[4] = {{0.f,0.f,0.f,0.f},{0.f,0.f,0.f,0.f},{0.f,0.f,0.f,0.f},{0.f,0.f,0.f,0.f}};
    u16* pbh = (u16*)(smem + 65536) + w * 640;            // stride-40 rows
    const int* mP = mp + 32 * wk + 4 * g;
    const float* bP = bias2 + h * 4096 + 2047 - qq + 32 * wk + 4 * g;
    float* pP = p_out + (size_t)bh * (S_LEN * S_LEN) + (size_t)qq * S_LEN + 32 * wk + 4 * g;
    const int kAoff0 = (32 * wk + lq) * 128;              // K frag byte base (+t2*2048)
    const int voffb = lq * 128 + ((4 * wk + g) ^ r7) * 16; // V frag byte base (+n*2048)
    u16* pwr = pbh + lq * 40 + g * 4;                     // p write (+t2*16)
    const u16* prd = pbh + lq * 40 + g * 8;               // p frag read

    for (int t = 0; t < 32; ++t) {
        const int cb = (t & 1) * 32768;
        // hoist mask/bias loads BEFORE staging (in-order vmcnt: their use-waits
        // then leave the newer gl_lds outstanding)
        int4 mv[2]; float bv[2][4];
        #pragma unroll
        for (int t2 = 0; t2 < 2; ++t2) {
            mv[t2] = *(const int4*)(mP + 16 * t2);
            #pragma unroll
            for (int j = 0; j < 4; ++j) bv[t2][j] = bP[16 * t2 + j];
        }
        if (t < 31) {
            sKh += 4096; sKl += 4096; sVh += 64; sVl += 64;
            char* d0 = smem + ((t + 1) & 1) * 32768 + tid * 16;
            gl_lds16(sKh, d0);
            gl_lds16(sKl, d0 + 8192);
            gl_lds16(sVh, d0 + 16384);
            gl_lds16(sVl, d0 + 24576);
        }
        __builtin_amdgcn_sched_barrier(0);   // pin: staging issued before any NT store
        #pragma unroll
        for (int t2 = 0; t2 < 2; ++t2) {
            const char* kbase = smem + cb + kAoff0 + t2 * 2048;
            f32x4 acc = {0.f, 0.f, 0.f, 0.f};
            #pragma unroll
            for (int c = 0; c < 2; ++c) {
                int blk = ((4 * c + g) ^ r7) * 16;
                short8 ah = *(const short8*)(kbase + blk);
                short8 al = *(const short8*)(kbase + 8192 + blk);
                acc = __builtin_amdgcn_mfma_f32_16x16x32_bf16(ah, qfh[c], acc, 0, 0, 0);
                acc = __builtin_amdgcn_mfma_f32_16x16x32_bf16(al, qfh[c], acc, 0, 0, 0);
                acc = __builtin_amdgcn_mfma_f32_16x16x32_bf16(ah, qfl[c], acc, 0, 0, 0);
            }
            float p0 = exp2v(mv[t2].x ? fmaf(acc[0], C2, bv[t2][0]) + lr2q : -1e9f);
            float p1 = exp2v(mv[t2].y ? fmaf(acc[1], C2, bv[t2][1]) + lr2q : -1e9f);
            float p2 = exp2v(mv[t2].z ? fmaf(acc[2], C2, bv[t2][2]) + lr2q : -1e9f);
            float p3 = exp2v(mv[t2].w ? fmaf(acc[3], C2, bv[t2][3]) + lr2q : -1e9f);
            f32x4 pw = {p0, p1, p2, p3};
            __builtin_nontemporal_store(pw, (f32x4*)(pP + 16 * t2));
            short4v ph4;
            ph4[0] = (short)bfbits(p0);
            ph4[1] = (short)bfbits(p1);
            ph4[2] = (short)bfbits(p2);
            ph4[3] = (short)bfbits(p3);
            *(short4v*)(pwr + 16 * t2) = ph4;
        }
        // PV: A = P-hi [16q x 32k] (own wave's LDS), B = V^T hi/lo
        const short8 pf = *(const short8*)prd;
        #pragma unroll
        for (int n = 0; n < 4; ++n) {
            const char* vb = smem + cb + 16384 + voffb + n * 2048;
            short8 bhf = *(const short8*)vb;
            short8 blf = *(const short8*)(vb + 8192);
            acco[n] = __builtin_amdgcn_mfma_f32_16x16x32_bf16(pf, bhf, acco[n], 0, 0, 0);
            acco[n] = __builtin_amdgcn_mfma_f32_16x16x32_bf16(pf, blf, acco[n], 0, 0, 0);
        }
        mP += 64; bP += 64; pP += 64;
        // counted end-of-iter: 4 staging gl_lds done, <=2 NT stores stay in flight
        asm volatile("s_waitcnt vmcnt(2)" ::: "memory");
        __builtin_amdgcn_sched_barrier(0);
        __builtin_amdgcn_s_barrier();
        __builtin_amdgcn_sched_barrier(0);
    }

    // ---- reduce the two wk halves (stage area is dead) and store out ----
    float* ored = (float*)smem;    // [64 q][64 d]
    __syncthreads();
    if (wk == 1) {
        #pragma unroll
        for (int n = 0; n < 4; ++n)
            #pragma unroll
            for (int r = 0; r < 4; ++r)
                ored[(wq * 16 + 4 * g + r) * 64 + 16 * n + lq] = acco[n][r];
    }
    __syncthreads();
    if (wk == 0) {
        #pragma unroll
        for (int n = 0; n < 4; ++n) {
            #pragma unroll
            for (int r = 0; r < 4; ++r) {
                float v = acco[n][r] + ored[(wq * 16 + 4 * g + r) * 64 + 16 * n + lq];
                outp[((size_t)bh * S_LEN + q0 + 16 * wq + 4 * g + r) * D_HEAD + 16 * n + lq] = v;
            }
        }
    }
}

extern "C" void kernel_launch(void* const* d_in, const int* in_sizes, int n_in,
                              void* d_out, int out_size, void* d_ws, size_t ws_size,
                              hipStream_t stream) {
    const float* Q = (const float*)d_in[0];
    const float* K = (const float*)d_in[1];
    const float* V = (const float*)d_in[2];
    const int* mask = (const int*)d_in[3];
    const float* table = (const float*)d_in[4];

    float* outp = (float*)d_out;
    float* p_out = outp + (size_t)4 * 4 * 2048 * 64;   // out first, then p_attn

    float* bias_d = (float*)d_ws;                                   // 64 KB
    u16* khi = (u16*)((char*)d_ws + 65536);                         // 4 MB each
    u16* klo = khi + (size_t)16 * S_LEN * D_HEAD;
    u16* vthi = klo + (size_t)16 * S_LEN * D_HEAD;
    u16* vtlo = vthi + (size_t)16 * S_LEN * D_HEAD;

    prep_bias<<<16, 256, 0, stream>>>(table, bias_d);
    prep_split<<<1024, 256, 0, stream>>>(K, khi, klo);
    prep_vt<<<dim3(32, 16), 256, 0, stream>>>(V, vthi, vtlo);
    attn_main<<<512, 512, 0, stream>>>(Q, mask, bias_d, khi, klo, vthi, vtlo, outp, p_out);
}

// Round 6
// 134.517 us; speedup vs baseline: 2.7137x; 1.0120x over previous
//
#include <hip/hip_runtime.h>
#include <math.h>

typedef __attribute__((ext_vector_type(8))) short short8;
typedef __attribute__((ext_vector_type(4))) float f32x4;
typedef _Float16 f16x8 __attribute__((ext_vector_type(8)));
typedef _Float16 f16x4v __attribute__((ext_vector_type(4)));
typedef unsigned short u16;

#define S_LEN 2048
#define D_HEAD 64
#define C2 0.18033688011112043f   /* log2(e)/8 */

static __device__ __forceinline__ float exp2v(float x) { // v_exp_f32 = 2^x
    float r; asm("v_exp_f32 %0, %1" : "=v"(r) : "v"(x)); return r;
}

static __device__ __forceinline__ void gl_lds16(const void* g, void* l) {
    __builtin_amdgcn_global_load_lds(
        (const __attribute__((address_space(1))) unsigned int*)g,
        (__attribute__((address_space(3))) unsigned int*)l, 16, 0, 0);
}

// ---- prep: T5 bias baked to [h][delta+2047], pre-scaled by log2(e)/8 ----
__global__ void prep_bias(const float* __restrict__ table, float* __restrict__ bias_d) {
    int idx = blockIdx.x * blockDim.x + threadIdx.x;   // 0..4095
    if (idx >= 4096) return;
    int delta = idx - 2047;                 // k - q
    int bpos = (delta > 0) ? 16 : 0;
    int ad = delta < 0 ? -delta : delta;
    int rel;
    if (ad < 8) {
        rel = bpos + ad;
    } else {
        float rp = (float)ad;
        int lg = 8 + (int)(logf(rp / 8.0f) / 2.772588722239781f * 8.0f);  // log(16)
        if (lg > 15) lg = 15;
        rel = bpos + lg;
    }
    #pragma unroll
    for (int h = 0; h < 4; ++h)
        bias_d[h * 4096 + idx] = C2 * table[rel * 4 + h];
}

// ---- prep: elementwise fp32 -> fp16 (for K) ----
__global__ void prep_half(const float* __restrict__ src, _Float16* __restrict__ dst) {
    size_t i8 = ((size_t)blockIdx.x * 256 + threadIdx.x) * 8;
    f32x4 a = *(const f32x4*)(src + i8);
    f32x4 b = *(const f32x4*)(src + i8 + 4);
    f16x8 h;
    h[0] = (_Float16)a[0]; h[1] = (_Float16)a[1];
    h[2] = (_Float16)a[2]; h[3] = (_Float16)a[3];
    h[4] = (_Float16)b[0]; h[5] = (_Float16)b[1];
    h[6] = (_Float16)b[2]; h[7] = (_Float16)b[3];
    *(f16x8*)(dst + i8) = h;
}

// ---- prep: V [bh][k][d] fp32  ->  V^T fp16 [bh][d][k] ----
__global__ void prep_vt(const float* __restrict__ V, _Float16* __restrict__ vt) {
    __shared__ float tile[64][65];
    const int bh = blockIdx.y;
    const int k0 = blockIdx.x * 64;
    const int t = threadIdx.x;
    {
        int r = t >> 2, c0 = (t & 3) * 16;
        const float* src = V + ((size_t)bh * S_LEN + k0 + r) * D_HEAD + c0;
        #pragma unroll
        for (int i = 0; i < 16; i += 4) {
            f32x4 v = *(const f32x4*)(src + i);
            tile[r][c0 + i + 0] = v[0];
            tile[r][c0 + i + 1] = v[1];
            tile[r][c0 + i + 2] = v[2];
            tile[r][c0 + i + 3] = v[3];
        }
    }
    __syncthreads();
    {
        int d = t >> 2, kc = (t & 3) * 16;
        size_t ob = ((size_t)bh * D_HEAD + d) * S_LEN + k0 + kc;
        #pragma unroll
        for (int half = 0; half < 2; ++half) {
            f16x8 hv;
            #pragma unroll
            for (int i = 0; i < 8; ++i)
                hv[i] = (_Float16)tile[kc + half * 8 + i][d];
            *(f16x8*)(vt + ob + half * 8) = hv;
        }
    }
}

// ============================================================================
// main: two-pass fused attention, log2-domain max-free softmax, all-fp16
// operands (K,V,Q,P as f16; 2^-11 rounding beats bf16-hi/lo in error AND
// cost). Pass1 and pass2 compute BIT-IDENTICAL scores -> sum(p)=1 to fp32
// rounding. Counted vmcnt + raw s_barrier per iter (r5's proven win).
// LDS 43.5KB -> 3 blocks/CU (24 waves):
//   [0..32K)      staging dbuf. pass1: K128 tile 16KB each. pass2: {K64 8KB,
//                 V64 8KB} each. Q f16 staged at [0..8K) before pass1.
//   [32K..42.25K) per-wave p-f16 buffers, 16 rows x 40 f16.
//   [42.25K..42.75K) stats.
// Tiles XOR-swizzled via pre-swizzled GLOBAL source addrs (rule #21).
// ============================================================================
__launch_bounds__(512, 6)
__global__ void attn_main(const float* __restrict__ Q, const int* __restrict__ mask,
                          const float* __restrict__ bias2,
                          const _Float16* __restrict__ kh_g,
                          const _Float16* __restrict__ vt_g,
                          float* __restrict__ outp, float* __restrict__ p_out) {
    __shared__ __align__(16) char smem[43520];
    float* stats = (float*)(smem + 43008);    // 128 floats

    const int tid = threadIdx.x;
    const int w = tid >> 6, l = tid & 63;
    const int wq = w & 3, wk = w >> 2;
    const int g = l >> 4, lq = l & 15;
    const int r7 = lq & 7;
    const int bid = blockIdx.x;
    const int bh = bid & 15, b = bh >> 2, h = bh & 3;   // bid%8 == bh%8: bh pinned per XCD
    const int q0 = (bid >> 4) * 64;

    const float* Qp = Q + (size_t)bh * (S_LEN * D_HEAD);
    const int* mp = mask + b * S_LEN;
    const _Float16* khp = kh_g + (size_t)bh * (S_LEN * D_HEAD);
    const _Float16* vhp = vt_g + (size_t)bh * (S_LEN * D_HEAD);

    // ---- stage Q -> f16 (swizzled ds_write) at smem[0..8K) ----
    _Float16* qarea = (_Float16*)smem;
    {
        int sr = tid >> 3, tb = tid & 7;
        const float* src = Qp + (size_t)(q0 + sr) * D_HEAD + tb * 8;
        f32x4 a = *(const f32x4*)src;
        f32x4 c = *(const f32x4*)(src + 4);
        f16x8 hv;
        hv[0] = (_Float16)a[0]; hv[1] = (_Float16)a[1];
        hv[2] = (_Float16)a[2]; hv[3] = (_Float16)a[3];
        hv[4] = (_Float16)c[0]; hv[5] = (_Float16)c[1];
        hv[6] = (_Float16)c[2]; hv[7] = (_Float16)c[3];
        *(f16x8*)(qarea + sr * 64 + ((tb ^ (sr & 7)) * 8)) = hv;
    }
    __syncthreads();
    f16x8 qf[2];
    const int qrow = 16 * wq + lq;
    #pragma unroll
    for (int c = 0; c < 2; ++c)
        qf[c] = *(const f16x8*)(qarea + qrow * 64 + ((4 * c + g) ^ r7) * 8);
    __syncthreads();   // all Q reads done before staging overwrites [0..8K)

    const int qq = q0 + qrow;

    // hoisted staging geometry
    const int rr3 = tid >> 3;                       // chunk row 0..63
    const int ub0 = (((tid & 7) ^ (rr3 & 7)) * 8);  // swizzled 8-elem block
    // pass-1 prologue: stage K rows 0..127 -> smem[0..16K)
    const _Float16* s1a = khp + (size_t)rr3 * 64 + ub0;
    gl_lds16(s1a, smem + tid * 16);
    gl_lds16(s1a + 4096, smem + 8192 + tid * 16);
    __syncthreads();   // full drain, once

    // ================= PASS 1: l = sum(2^s2), K-tile 128, 16 iters =================
    const int* mP1 = mp + 64 * wk + 4 * g;
    const float* bP1 = bias2 + h * 4096 + 2047 - qq + 64 * wk + 4 * g;
    float lsum = 0.0f;
    for (int t = 0; t < 16; ++t) {
        const char* kb = smem + (t & 1) * 16384;
        int4 mv[4]; float bv[4][4];
        #pragma unroll
        for (int t2 = 0; t2 < 4; ++t2) {
            mv[t2] = *(const int4*)(mP1 + 16 * t2);
            #pragma unroll
            for (int j = 0; j < 4; ++j) bv[t2][j] = bP1[16 * t2 + j];
        }
        if (t < 15) {
            s1a += 8192;
            char* nb = smem + ((t + 1) & 1) * 16384 + tid * 16;
            gl_lds16(s1a, nb);
            gl_lds16(s1a + 4096, nb + 8192);
        }
        __builtin_amdgcn_sched_barrier(0);
        #pragma unroll
        for (int t2 = 0; t2 < 4; ++t2) {
            const int krow = 64 * wk + 16 * t2 + lq;
            f32x4 acc = {0.f, 0.f, 0.f, 0.f};
            #pragma unroll
            for (int c = 0; c < 2; ++c) {
                f16x8 af = *(const f16x8*)(kb + krow * 128 + ((4 * c + g) ^ r7) * 16);
                acc = __builtin_amdgcn_mfma_f32_16x16x32_f16(af, qf[c], acc, 0, 0, 0);
            }
            float s0 = mv[t2].x ? fmaf(acc[0], C2, bv[t2][0]) : -1e9f;
            float s1 = mv[t2].y ? fmaf(acc[1], C2, bv[t2][1]) : -1e9f;
            float s2 = mv[t2].z ? fmaf(acc[2], C2, bv[t2][2]) : -1e9f;
            float s3 = mv[t2].w ? fmaf(acc[3], C2, bv[t2][3]) : -1e9f;
            lsum += exp2v(s0) + exp2v(s1) + exp2v(s2) + exp2v(s3);
        }
        mP1 += 128; bP1 += 128;
        asm volatile("s_waitcnt vmcnt(0)" ::: "memory");
        __builtin_amdgcn_sched_barrier(0);
        __builtin_amdgcn_s_barrier();
        __builtin_amdgcn_sched_barrier(0);
    }
    lsum += __shfl_xor(lsum, 16);
    lsum += __shfl_xor(lsum, 32);
    if (g == 0) stats[wk * 64 + qrow] = lsum;

    // ---- pass-2 staging pointers + prologue (buf0: K64, V64) ----
    const _Float16* sKh = khp + (size_t)rr3 * 64 + ub0;
    const _Float16* sVh = vhp + (size_t)rr3 * 2048 + ub0;
    gl_lds16(sKh, smem + tid * 16);
    gl_lds16(sVh, smem + 8192 + tid * 16);
    __syncthreads();   // stats visible + buf0 staged (full drain, once)
    float lr2q;
    {
        float L = stats[qrow] + stats[64 + qrow];
        float lg; asm("v_log_f32 %0, %1" : "=v"(lg) : "v"(L));
        lr2q = -lg;    // p = 2^(s2 + lr2q)
    }

    // ================= PASS 2: p = 2^(s2+lr2), write p, PV (all f16) =================
    f32x4 acco[4] = {{0.f,0.f,0.f,0.f},{0.f,0.f,0.f,0.f},{0.f,0.f,0.f,0.f},{0.f,0.f,0.f,0.f}};
    _Float16* pbh = (_Float16*)(smem + 32768) + w * 640;   // stride-40 rows
    const int* mP = mp + 32 * wk + 4 * g;
    const float* bP = bias2 + h * 4096 + 2047 - qq + 32 * wk + 4 * g;
    float* pP = p_out + (size_t)bh * (S_LEN * S_LEN) + (size_t)qq * S_LEN + 32 * wk + 4 * g;
    const int kAoff0 = (32 * wk + lq) * 128;               // K frag byte base (+t2*2048)
    const int voffb = lq * 128 + ((4 * wk + g) ^ r7) * 16; // V frag byte base (+n*2048)
    _Float16* pwr = pbh + lq * 40 + g * 4;                 // p write (+t2*16)
    const _Float16* prd = pbh + lq * 40 + g * 8;           // p frag read

    for (int t = 0; t < 32; ++t) {
        const int cb = (t & 1) * 16384;
        int4 mv[2]; float bv[2][4];
        #pragma unroll
        for (int t2 = 0; t2 < 2; ++t2) {
            mv[t2] = *(const int4*)(mP + 16 * t2);
            #pragma unroll
            for (int j = 0; j < 4; ++j) bv[t2][j] = bP[16 * t2 + j];
        }
        if (t < 31) {
            sKh += 4096; sVh += 64;
            char* d0 = smem + ((t + 1) & 1) * 16384 + tid * 16;
            gl_lds16(sKh, d0);
            gl_lds16(sVh, d0 + 8192);
        }
        __builtin_amdgcn_sched_barrier(0);
        #pragma unroll
        for (int t2 = 0; t2 < 2; ++t2) {
            const char* kbase = smem + cb + kAoff0 + t2 * 2048;
            f32x4 acc = {0.f, 0.f, 0.f, 0.f};
            #pragma unroll
            for (int c = 0; c < 2; ++c) {
                f16x8 ah = *(const f16x8*)(kbase + ((4 * c + g) ^ r7) * 16);
                acc = __builtin_amdgcn_mfma_f32_16x16x32_f16(ah, qf[c], acc, 0, 0, 0);
            }
            float p0 = exp2v(mv[t2].x ? fmaf(acc[0], C2, bv[t2][0]) + lr2q : -1e9f);
            float p1 = exp2v(mv[t2].y ? fmaf(acc[1], C2, bv[t2][1]) + lr2q : -1e9f);
            float p2 = exp2v(mv[t2].z ? fmaf(acc[2], C2, bv[t2][2]) + lr2q : -1e9f);
            float p3 = exp2v(mv[t2].w ? fmaf(acc[3], C2, bv[t2][3]) + lr2q : -1e9f);
            f32x4 pw = {p0, p1, p2, p3};
            __builtin_nontemporal_store(pw, (f32x4*)(pP + 16 * t2));
            f16x4v ph4;
            ph4[0] = (_Float16)p0; ph4[1] = (_Float16)p1;
            ph4[2] = (_Float16)p2; ph4[3] = (_Float16)p3;
            *(f16x4v*)(pwr + 16 * t2) = ph4;
        }
        // PV: A = P-f16 [16q x 32k] (own wave's LDS), B = V^T f16
        const f16x8 pf = *(const f16x8*)prd;
        #pragma unroll
        for (int n = 0; n < 4; ++n) {
            const f16x8 bhf = *(const f16x8*)(smem + cb + 8192 + voffb + n * 2048);
            acco[n] = __builtin_amdgcn_mfma_f32_16x16x32_f16(pf, bhf, acco[n], 0, 0, 0);
        }
        mP += 64; bP += 64; pP += 64;
        // counted end-of-iter: 2 staging gl_lds done, <=2 NT stores stay in flight
        asm volatile("s_waitcnt vmcnt(2)" ::: "memory");
        __builtin_amdgcn_sched_barrier(0);
        __builtin_amdgcn_s_barrier();
        __builtin_amdgcn_sched_barrier(0);
    }

    // ---- reduce the two wk halves (stage area is dead) and store out ----
    float* ored = (float*)smem;    // [64 q][64 d]
    __syncthreads();
    if (wk == 1) {
        #pragma unroll
        for (int n = 0; n < 4; ++n)
            #pragma unroll
            for (int r = 0; r < 4; ++r)
                ored[(wq * 16 + 4 * g + r) * 64 + 16 * n + lq] = acco[n][r];
    }
    __syncthreads();
    if (wk == 0) {
        #pragma unroll
        for (int n = 0; n < 4; ++n) {
            #pragma unroll
            for (int r = 0; r < 4; ++r) {
                float v = acco[n][r] + ored[(wq * 16 + 4 * g + r) * 64 + 16 * n + lq];
                outp[((size_t)bh * S_LEN + q0 + 16 * wq + 4 * g + r) * D_HEAD + 16 * n + lq] = v;
            }
        }
    }
}

extern "C" void kernel_launch(void* const* d_in, const int* in_sizes, int n_in,
                              void* d_out, int out_size, void* d_ws, size_t ws_size,
                              hipStream_t stream) {
    const float* Q = (const float*)d_in[0];
    const float* K = (const float*)d_in[1];
    const float* V = (const float*)d_in[2];
    const int* mask = (const int*)d_in[3];
    const float* table = (const float*)d_in[4];

    float* outp = (float*)d_out;
    float* p_out = outp + (size_t)4 * 4 * 2048 * 64;   // out first, then p_attn

    float* bias_d = (float*)d_ws;                                   // 64 KB
    _Float16* kh = (_Float16*)((char*)d_ws + 65536);                // 4 MB
    _Float16* vt = kh + (size_t)16 * S_LEN * D_HEAD;                // 4 MB

    prep_bias<<<16, 256, 0, stream>>>(table, bias_d);
    prep_half<<<1024, 256, 0, stream>>>(K, kh);
    prep_vt<<<dim3(32, 16), 256, 0, stream>>>(V, vt);
    attn_main<<<512, 512, 0, stream>>>(Q, mask, bias_d, kh, vt, outp, p_out);
}